// Round 5
// baseline (182.887 us; speedup 1.0000x reference)
//
#include <hip/hip_runtime.h>

#define BB 16384
#define KK 64
#define DD 128
#define SEG 128          // rows per covariance work-item
#define MAXITEMS 256     // sum_k ceil(cnt_k/SEG) <= 128 + 63 = 191

// ---------------------------------------------------------------------------
// K1: tiled GEMM. Block = 64 rows x 64 clusters, K=128.
// dist = |x|^2 - 2 x.c + |c|^2 ; |x|^2 cancels in softmax AND argmin.
// Also zeroes outscalars + emp[] (consumed >=2 dispatches later).
// ---------------------------------------------------------------------------
__global__ __launch_bounds__(256) void k_rows(
    const float* __restrict__ x, const float* __restrict__ centers,
    float* __restrict__ log_resp, int* __restrict__ assign,
    float* __restrict__ outscalars, float* __restrict__ emp)
{
    __shared__ float xs[64][132];    // X tile, +4 pad
    __shared__ float ct[DD][66];     // centers transposed [d][k]
    __shared__ float cn2[KK];

    const int tid = threadIdx.x;
    const int row0 = blockIdx.x * 64;

    if (blockIdx.x == 0 && tid < 2) outscalars[tid] = 0.f;
    if (tid < 32) emp[blockIdx.x * 32 + tid] = 0.f;   // 256*32 = 8192

    for (int g = tid; g < 64 * 32; g += 256) {
        int r = g >> 5, c4 = g & 31;
        float4 v = ((const float4*)(x + (size_t)(row0 + r) * DD))[c4];
        *(float4*)&xs[r][c4 * 4] = v;
    }
    for (int g = tid; g < KK * 32; g += 256) {
        int k = g >> 5, c4 = g & 31;
        float4 v = ((const float4*)(centers + (size_t)k * DD))[c4];
        ct[c4 * 4 + 0][k] = v.x;
        ct[c4 * 4 + 1][k] = v.y;
        ct[c4 * 4 + 2][k] = v.z;
        ct[c4 * 4 + 3][k] = v.w;
    }
    __syncthreads();
    if (tid < KK) {
        float s = 0.f;
        for (int d = 0; d < DD; ++d) { float c = ct[d][tid]; s = fmaf(c, c, s); }
        cn2[tid] = s;
    }
    __syncthreads();

    const int tr = tid >> 5;
    const int tc = tid & 31;
    const int k0 = tc * 2, k1 = k0 + 1;

    float acc0[8], acc1[8];
    #pragma unroll
    for (int i = 0; i < 8; ++i) { acc0[i] = 0.f; acc1[i] = 0.f; }

    for (int d = 0; d < DD; d += 4) {
        float2 b0 = *(const float2*)&ct[d + 0][k0];
        float2 b1 = *(const float2*)&ct[d + 1][k0];
        float2 b2 = *(const float2*)&ct[d + 2][k0];
        float2 b3 = *(const float2*)&ct[d + 3][k0];
        #pragma unroll
        for (int i = 0; i < 8; ++i) {
            float4 a = *(const float4*)&xs[tr * 8 + i][d];
            acc0[i] = fmaf(a.x, b0.x, acc0[i]);
            acc1[i] = fmaf(a.x, b0.y, acc1[i]);
            acc0[i] = fmaf(a.y, b1.x, acc0[i]);
            acc1[i] = fmaf(a.y, b1.y, acc1[i]);
            acc0[i] = fmaf(a.z, b2.x, acc0[i]);
            acc1[i] = fmaf(a.z, b2.y, acc1[i]);
            acc0[i] = fmaf(a.w, b3.x, acc0[i]);
            acc1[i] = fmaf(a.w, b3.y, acc1[i]);
        }
    }

    const float cn0 = 0.5f * cn2[k0], cn1 = 0.5f * cn2[k1];
    #pragma unroll
    for (int i = 0; i < 8; ++i) {
        int row = row0 + tr * 8 + i;
        float v0 = acc0[i] - cn0;
        float v1 = acc1[i] - cn1;
        float m; int idx;
        if (v1 > v0) { m = v1; idx = k1; } else { m = v0; idx = k0; }
        #pragma unroll
        for (int off = 1; off < 32; off <<= 1) {
            float ov = __shfl_xor(m, off);
            int   oi = __shfl_xor(idx, off);
            if (ov > m || (ov == m && oi < idx)) { m = ov; idx = oi; }
        }
        float s = expf(v0 - m) + expf(v1 - m);
        #pragma unroll
        for (int off = 1; off < 32; off <<= 1) s += __shfl_xor(s, off);
        float ls = logf(s);
        float lr0 = fmaxf(v0 - m - ls, -18.4206807f);  // log(1e-8)
        float lr1 = fmaxf(v1 - m - ls, -18.4206807f);
        *(float2*)&log_resp[(size_t)row * KK + k0] = make_float2(lr0, lr1);
        if (tc == 0) assign[row] = idx;
    }
}

// ---------------------------------------------------------------------------
// K2 (1 block, 1024 threads): counting sort by cluster + work items + ranges.
// ---------------------------------------------------------------------------
__global__ __launch_bounds__(1024) void k_sort(
    const int* __restrict__ assign, int* __restrict__ sorted,
    float* __restrict__ cw, int4* __restrict__ items, int* __restrict__ item_count,
    int* __restrict__ ist, int* __restrict__ ien)
{
    __shared__ int whist[16][64];
    __shared__ int wcur[16][64];
    __shared__ int cnt_s[64];
    __shared__ int cbase_s[64];

    const int tid = threadIdx.x;
    const int w = tid >> 6;
    const int lane = tid & 63;

    whist[w][lane] = 0;
    __syncthreads();

    #pragma unroll
    for (int i = 0; i < 16; ++i) {
        int r = w * 1024 + i * 64 + lane;
        atomicAdd(&whist[w][assign[r]], 1);
    }
    __syncthreads();

    if (tid < 64) {
        int run = 0;
        #pragma unroll
        for (int ww = 0; ww < 16; ++ww) {
            int t = whist[ww][tid];
            whist[ww][tid] = run;
            run += t;
        }
        cnt_s[tid] = run;
        cw[tid] = (float)run;
    }
    __syncthreads();

    if (tid == 0) {
        int base = 0;
        for (int k = 0; k < KK; ++k) { cbase_s[k] = base; base += cnt_s[k]; }
        int ic = 0;
        for (int k = 0; k < KK; ++k) {
            ist[k] = ic;
            int c = cnt_s[k];
            for (int s = 0; s < c; s += SEG) {
                int4 it; it.x = k; it.y = cbase_s[k] + s;
                it.z = min(SEG, c - s); it.w = 0;
                items[ic++] = it;
            }
            ien[k] = ic;
        }
        *item_count = ic;
    }
    __syncthreads();

    wcur[w][lane] = cbase_s[lane] + whist[w][lane];
    __syncthreads();

    #pragma unroll
    for (int i = 0; i < 16; ++i) {
        int r = w * 1024 + i * 64 + lane;
        int a = assign[r];
        int p = atomicAdd(&wcur[w][a], 1);
        sorted[p] = r;
    }
}

// ---------------------------------------------------------------------------
// K3: one block per item (<=128 rows), FULL 128x128 partial via 8x8 thread
// tiles (64 FMA per 64B LDS read). Register prefetch of the next 8-row chunk
// hides the scattered global x latency behind the compute. Column sums go
// straight to emp[] via atomics (zeroed by k_rows).
// ---------------------------------------------------------------------------
__global__ __launch_bounds__(256) void k_seg(
    const float* __restrict__ x, const int* __restrict__ sorted,
    const int4* __restrict__ items, const int* __restrict__ item_count,
    float* __restrict__ part, float* __restrict__ emp)
{
    if ((int)blockIdx.x >= *item_count) return;
    int4 it = items[blockIdx.x];
    const int k = it.x, gstart = it.y, len = it.z;

    __shared__ int rows_s[SEG];
    __shared__ float xr_s[8][DD];

    const int tid = threadIdx.x;
    if (tid < len) rows_s[tid] = sorted[gstart + tid];

    const int jrow = tid >> 5;            // 0..7: staged row this thread loads
    const int dc   = (tid & 31) * 4;      // float4 column offset
    const int tr = tid >> 4, tc = tid & 15;

    float acc[8][8];
    #pragma unroll
    for (int i = 0; i < 8; ++i)
        #pragma unroll
        for (int l = 0; l < 8; ++l) acc[i][l] = 0.f;
    float cs0 = 0.f, cs1 = 0.f, cs2 = 0.f, cs3 = 0.f;

    __syncthreads();   // rows_s ready

    float4 cur = {0.f, 0.f, 0.f, 0.f};
    if (jrow < len)
        cur = *(const float4*)(x + (size_t)rows_s[jrow] * DD + dc);

    for (int it0 = 0; it0 < len; it0 += 8) {
        __syncthreads();   // WAR on xr_s
        *(float4*)&xr_s[jrow][dc] = cur;
        cs0 += cur.x; cs1 += cur.y; cs2 += cur.z; cs3 += cur.w;
        __syncthreads();   // RAW

        // prefetch next chunk (retires behind the compute below)
        float4 nxt = {0.f, 0.f, 0.f, 0.f};
        int mi = it0 + 8 + jrow;
        if (mi < len)
            nxt = *(const float4*)(x + (size_t)rows_s[mi] * DD + dc);

        #pragma unroll
        for (int j = 0; j < 8; ++j) {
            float4 a0 = *(const float4*)&xr_s[j][tr * 8];
            float4 a1 = *(const float4*)&xr_s[j][tr * 8 + 4];
            float4 b0 = *(const float4*)&xr_s[j][tc * 8];
            float4 b1 = *(const float4*)&xr_s[j][tc * 8 + 4];
            float av[8] = {a0.x, a0.y, a0.z, a0.w, a1.x, a1.y, a1.z, a1.w};
            float bv[8] = {b0.x, b0.y, b0.z, b0.w, b1.x, b1.y, b1.z, b1.w};
            #pragma unroll
            for (int i = 0; i < 8; ++i)
                #pragma unroll
                for (int l = 0; l < 8; ++l)
                    acc[i][l] = fmaf(av[i], bv[l], acc[i][l]);
        }
        cur = nxt;
    }

    float* pb = part + (size_t)blockIdx.x * (DD * DD);
    #pragma unroll
    for (int i = 0; i < 8; ++i) {
        #pragma unroll
        for (int l = 0; l < 8; l += 4)
            *(float4*)&pb[(tr * 8 + i) * DD + tc * 8 + l] = *(float4*)&acc[i][l];
    }

    // column sums: reduce 8 jrow-group partials via LDS, atomic into emp
    __syncthreads();
    xr_s[jrow][dc + 0] = cs0; xr_s[jrow][dc + 1] = cs1;
    xr_s[jrow][dc + 2] = cs2; xr_s[jrow][dc + 3] = cs3;
    __syncthreads();
    if (tid < 32) {
        float4 t = {0.f, 0.f, 0.f, 0.f};
        #pragma unroll
        for (int j = 0; j < 8; ++j) {
            float4 v = *(const float4*)&xr_s[j][tid * 4];
            t.x += v.x; t.y += v.y; t.z += v.z; t.w += v.w;
        }
        atomicAdd(&emp[k * DD + tid * 4 + 0], t.x);
        atomicAdd(&emp[k * DD + tid * 4 + 1], t.y);
        atomicAdd(&emp[k * DD + tid * 4 + 2], t.z);
        atomicAdd(&emp[k * DD + tid * 4 + 3], t.w);
    }
}

// ---------------------------------------------------------------------------
// K4: 32 blocks per cluster, each owns a 512-element slab (float2/thread).
// Sum item partials, form centered covariance inline, accumulate scalars.
// ---------------------------------------------------------------------------
__global__ __launch_bounds__(256) void k_redfinal(
    const float* __restrict__ part, const float* __restrict__ emp,
    const float* __restrict__ cw, const float* __restrict__ centers,
    const int* __restrict__ ist, const int* __restrict__ ien,
    float* __restrict__ outscalars)
{
    const int k = blockIdx.x >> 5;
    const int p = blockIdx.x & 31;
    const int i0 = ist[k], i1 = ien[k];
    const int tid = threadIdx.x;
    const float w = cw[k];
    const float inv = 1.0f / (w + 1e-7f);

    __shared__ float mu_s[DD], emp_s[DD];
    if (tid < DD) {
        float e = emp[k * DD + tid];
        emp_s[tid] = e;
        mu_s[tid] = e * inv;
    }
    __syncthreads();

    const int i = p * 512 + tid * 2;      // 2 consecutive elems, same row d
    float2 sx = {0.f, 0.f};
    for (int it = i0; it < i1; ++it) {
        float2 v = *(const float2*)&part[(size_t)it * (DD * DD) + i];
        sx.x += v.x; sx.y += v.y;
    }

    const int d = i >> 7;
    const int e0 = i & 127;
    const float md = mu_s[d], ed = emp_s[d];
    float sv[2] = {sx.x, sx.y};
    float ds = 0.f, os = 0.f, mm = 0.f;
    #pragma unroll
    for (int l = 0; l < 2; ++l) {
        int e = e0 + l;
        float ctv = sv[l] - md * emp_s[e] - ed * mu_s[e] + w * md * mu_s[e];
        float v = ctv * inv;
        if (e == d) { float t = v - 1.f; ds += t * t; }
        else        { os += v * v; }
    }
    if (p == 0 && tid < DD) {
        float t = mu_s[tid] - centers[k * DD + tid];
        mm = t * t;
    }

    #pragma unroll
    for (int off = 32; off > 0; off >>= 1) {
        ds += __shfl_down(ds, off);
        os += __shfl_down(os, off);
        mm += __shfl_down(mm, off);
    }
    __shared__ float rds[4], ros[4], rmm[4];
    int wv = tid >> 6, ln = tid & 63;
    if (ln == 0) { rds[wv] = ds; ros[wv] = os; rmm[wv] = mm; }
    __syncthreads();
    if (tid == 0) {
        float DS = rds[0] + rds[1] + rds[2] + rds[3];
        float OS = ros[0] + ros[1] + ros[2] + ros[3];
        float MM = rmm[0] + rmm[1] + rmm[2] + rmm[3];
        const float bd = (float)BB * (float)DD;
        atomicAdd(&outscalars[0], w * MM / bd);
        atomicAdd(&outscalars[1], w * DS / bd + w * OS / (bd * (float)(DD - 1)));
    }
}

// ---------------------------------------------------------------------------
extern "C" void kernel_launch(void* const* d_in, const int* in_sizes, int n_in,
                              void* d_out, int out_size, void* d_ws, size_t ws_size,
                              hipStream_t stream) {
    const float* x = (const float*)d_in[0];
    const float* centers = (const float*)d_in[1];
    float* out = (float*)d_out;
    float* outscalars = out + (size_t)BB * KK;

    char* ws = (char*)d_ws;
    size_t off = 0;
    float* part    = (float*)(ws + off); off += (size_t)MAXITEMS * DD * DD * 4; // 16 MB
    float* emp     = (float*)(ws + off); off += KK * DD * 4;                    // 32 KB
    int*   sorted  = (int*)  (ws + off); off += BB * 4;
    int*   assign  = (int*)  (ws + off); off += BB * 4;
    int4*  items   = (int4*) (ws + off); off += MAXITEMS * 16;
    float* cw      = (float*)(ws + off); off += 256;
    int*   itemcnt = (int*)  (ws + off); off += 256;
    int*   ist     = (int*)  (ws + off); off += 256;
    int*   ien     = (int*)  (ws + off); off += 256;

    k_rows    <<<256, 256,  0, stream>>>(x, centers, out, assign, outscalars, emp);
    k_sort    <<<1,   1024, 0, stream>>>(assign, sorted, cw, items, itemcnt, ist, ien);
    k_seg     <<<MAXITEMS, 256, 0, stream>>>(x, sorted, items, itemcnt, part, emp);
    k_redfinal<<<KK * 32, 256, 0, stream>>>(part, emp, cw, centers, ist, ien,
                                            outscalars);
}

// Round 6
// 140.361 us; speedup vs baseline: 1.3030x; 1.3030x over previous
//
#include <hip/hip_runtime.h>

#define BB 16384
#define KK 64
#define DD 128
#define SEG 128          // rows per covariance work-item
#define MAXITEMS 256     // sum_k ceil(cnt_k/SEG) <= 128 + 63 = 191
#define RSLAB 2048       // elements per reduce slab (8 slabs of 128x128)

// ---------------------------------------------------------------------------
// K1: tiled GEMM. Block = 64 rows x 64 clusters, K=128.
// dist = |x|^2 - 2 x.c + |c|^2 ; |x|^2 cancels in softmax AND argmin.
// Also zeroes outscalars + emp[] (consumed >=2 dispatches later).
// ---------------------------------------------------------------------------
__global__ __launch_bounds__(256) void k_rows(
    const float* __restrict__ x, const float* __restrict__ centers,
    float* __restrict__ log_resp, int* __restrict__ assign,
    float* __restrict__ outscalars, float* __restrict__ emp)
{
    __shared__ float xs[64][132];    // X tile, +4 pad
    __shared__ float ct[DD][66];     // centers transposed [d][k]
    __shared__ float cn2[KK];

    const int tid = threadIdx.x;
    const int row0 = blockIdx.x * 64;

    if (blockIdx.x == 0 && tid < 2) outscalars[tid] = 0.f;
    if (tid < 32) emp[blockIdx.x * 32 + tid] = 0.f;   // 256*32 = 8192

    for (int g = tid; g < 64 * 32; g += 256) {
        int r = g >> 5, c4 = g & 31;
        float4 v = ((const float4*)(x + (size_t)(row0 + r) * DD))[c4];
        *(float4*)&xs[r][c4 * 4] = v;
    }
    for (int g = tid; g < KK * 32; g += 256) {
        int k = g >> 5, c4 = g & 31;
        float4 v = ((const float4*)(centers + (size_t)k * DD))[c4];
        ct[c4 * 4 + 0][k] = v.x;
        ct[c4 * 4 + 1][k] = v.y;
        ct[c4 * 4 + 2][k] = v.z;
        ct[c4 * 4 + 3][k] = v.w;
    }
    __syncthreads();
    if (tid < KK) {
        float s = 0.f;
        for (int d = 0; d < DD; ++d) { float c = ct[d][tid]; s = fmaf(c, c, s); }
        cn2[tid] = s;
    }
    __syncthreads();

    const int tr = tid >> 5;
    const int tc = tid & 31;
    const int k0 = tc * 2, k1 = k0 + 1;

    float acc0[8], acc1[8];
    #pragma unroll
    for (int i = 0; i < 8; ++i) { acc0[i] = 0.f; acc1[i] = 0.f; }

    for (int d = 0; d < DD; d += 4) {
        float2 b0 = *(const float2*)&ct[d + 0][k0];
        float2 b1 = *(const float2*)&ct[d + 1][k0];
        float2 b2 = *(const float2*)&ct[d + 2][k0];
        float2 b3 = *(const float2*)&ct[d + 3][k0];
        #pragma unroll
        for (int i = 0; i < 8; ++i) {
            float4 a = *(const float4*)&xs[tr * 8 + i][d];
            acc0[i] = fmaf(a.x, b0.x, acc0[i]);
            acc1[i] = fmaf(a.x, b0.y, acc1[i]);
            acc0[i] = fmaf(a.y, b1.x, acc0[i]);
            acc1[i] = fmaf(a.y, b1.y, acc1[i]);
            acc0[i] = fmaf(a.z, b2.x, acc0[i]);
            acc1[i] = fmaf(a.z, b2.y, acc1[i]);
            acc0[i] = fmaf(a.w, b3.x, acc0[i]);
            acc1[i] = fmaf(a.w, b3.y, acc1[i]);
        }
    }

    const float cn0 = 0.5f * cn2[k0], cn1 = 0.5f * cn2[k1];
    #pragma unroll
    for (int i = 0; i < 8; ++i) {
        int row = row0 + tr * 8 + i;
        float v0 = acc0[i] - cn0;
        float v1 = acc1[i] - cn1;
        float m; int idx;
        if (v1 > v0) { m = v1; idx = k1; } else { m = v0; idx = k0; }
        #pragma unroll
        for (int off = 1; off < 32; off <<= 1) {
            float ov = __shfl_xor(m, off);
            int   oi = __shfl_xor(idx, off);
            if (ov > m || (ov == m && oi < idx)) { m = ov; idx = oi; }
        }
        float s = expf(v0 - m) + expf(v1 - m);
        #pragma unroll
        for (int off = 1; off < 32; off <<= 1) s += __shfl_xor(s, off);
        float ls = logf(s);
        float lr0 = fmaxf(v0 - m - ls, -18.4206807f);  // log(1e-8)
        float lr1 = fmaxf(v1 - m - ls, -18.4206807f);
        *(float2*)&log_resp[(size_t)row * KK + k0] = make_float2(lr0, lr1);
        if (tc == 0) assign[row] = idx;
    }
}

// ---------------------------------------------------------------------------
// K2 (1 block, 1024 threads): counting sort by cluster + work items + ranges.
// ---------------------------------------------------------------------------
__global__ __launch_bounds__(1024) void k_sort(
    const int* __restrict__ assign, int* __restrict__ sorted,
    float* __restrict__ cw, int4* __restrict__ items, int* __restrict__ item_count,
    int* __restrict__ ist, int* __restrict__ ien)
{
    __shared__ int whist[16][64];
    __shared__ int wcur[16][64];
    __shared__ int cnt_s[64];
    __shared__ int cbase_s[64];

    const int tid = threadIdx.x;
    const int w = tid >> 6;
    const int lane = tid & 63;

    whist[w][lane] = 0;
    __syncthreads();

    #pragma unroll
    for (int i = 0; i < 16; ++i) {
        int r = w * 1024 + i * 64 + lane;
        atomicAdd(&whist[w][assign[r]], 1);
    }
    __syncthreads();

    if (tid < 64) {
        int run = 0;
        #pragma unroll
        for (int ww = 0; ww < 16; ++ww) {
            int t = whist[ww][tid];
            whist[ww][tid] = run;
            run += t;
        }
        cnt_s[tid] = run;
        cw[tid] = (float)run;
    }
    __syncthreads();

    if (tid == 0) {
        int base = 0;
        for (int k = 0; k < KK; ++k) { cbase_s[k] = base; base += cnt_s[k]; }
        int ic = 0;
        for (int k = 0; k < KK; ++k) {
            ist[k] = ic;
            int c = cnt_s[k];
            for (int s = 0; s < c; s += SEG) {
                int4 it; it.x = k; it.y = cbase_s[k] + s;
                it.z = min(SEG, c - s); it.w = 0;
                items[ic++] = it;
            }
            ien[k] = ic;
        }
        *item_count = ic;
    }
    __syncthreads();

    wcur[w][lane] = cbase_s[lane] + whist[w][lane];
    __syncthreads();

    #pragma unroll
    for (int i = 0; i < 16; ++i) {
        int r = w * 1024 + i * 64 + lane;
        int a = assign[r];
        int p = atomicAdd(&wcur[w][a], 1);
        sorted[p] = r;
    }
}

// ---------------------------------------------------------------------------
// K3: one block per item (<=128 rows), FULL 128x128 partial via 8x8 thread
// tiles. Register prefetch hides the scattered global x latency behind
// compute. Column sums atomically into emp[] (zeroed by k_rows).
// ---------------------------------------------------------------------------
__global__ __launch_bounds__(256) void k_seg(
    const float* __restrict__ x, const int* __restrict__ sorted,
    const int4* __restrict__ items, const int* __restrict__ item_count,
    float* __restrict__ part, float* __restrict__ emp)
{
    if ((int)blockIdx.x >= *item_count) return;
    int4 it = items[blockIdx.x];
    const int k = it.x, gstart = it.y, len = it.z;

    __shared__ int rows_s[SEG];
    __shared__ float xr_s[8][DD];

    const int tid = threadIdx.x;
    if (tid < len) rows_s[tid] = sorted[gstart + tid];

    const int jrow = tid >> 5;            // 0..7: staged row this thread loads
    const int dc   = (tid & 31) * 4;      // float4 column offset
    const int tr = tid >> 4, tc = tid & 15;

    float acc[8][8];
    #pragma unroll
    for (int i = 0; i < 8; ++i)
        #pragma unroll
        for (int l = 0; l < 8; ++l) acc[i][l] = 0.f;
    float cs0 = 0.f, cs1 = 0.f, cs2 = 0.f, cs3 = 0.f;

    __syncthreads();   // rows_s ready

    float4 cur = {0.f, 0.f, 0.f, 0.f};
    if (jrow < len)
        cur = *(const float4*)(x + (size_t)rows_s[jrow] * DD + dc);

    for (int it0 = 0; it0 < len; it0 += 8) {
        __syncthreads();   // WAR on xr_s
        *(float4*)&xr_s[jrow][dc] = cur;
        cs0 += cur.x; cs1 += cur.y; cs2 += cur.z; cs3 += cur.w;
        __syncthreads();   // RAW

        float4 nxt = {0.f, 0.f, 0.f, 0.f};
        int mi = it0 + 8 + jrow;
        if (mi < len)
            nxt = *(const float4*)(x + (size_t)rows_s[mi] * DD + dc);

        #pragma unroll
        for (int j = 0; j < 8; ++j) {
            float4 a0 = *(const float4*)&xr_s[j][tr * 8];
            float4 a1 = *(const float4*)&xr_s[j][tr * 8 + 4];
            float4 b0 = *(const float4*)&xr_s[j][tc * 8];
            float4 b1 = *(const float4*)&xr_s[j][tc * 8 + 4];
            float av[8] = {a0.x, a0.y, a0.z, a0.w, a1.x, a1.y, a1.z, a1.w};
            float bv[8] = {b0.x, b0.y, b0.z, b0.w, b1.x, b1.y, b1.z, b1.w};
            #pragma unroll
            for (int i = 0; i < 8; ++i)
                #pragma unroll
                for (int l = 0; l < 8; ++l)
                    acc[i][l] = fmaf(av[i], bv[l], acc[i][l]);
        }
        cur = nxt;
    }

    float* pb = part + (size_t)blockIdx.x * (DD * DD);
    #pragma unroll
    for (int i = 0; i < 8; ++i) {
        #pragma unroll
        for (int l = 0; l < 8; l += 4)
            *(float4*)&pb[(tr * 8 + i) * DD + tc * 8 + l] = *(float4*)&acc[i][l];
    }

    __syncthreads();
    xr_s[jrow][dc + 0] = cs0; xr_s[jrow][dc + 1] = cs1;
    xr_s[jrow][dc + 2] = cs2; xr_s[jrow][dc + 3] = cs3;
    __syncthreads();
    if (tid < 32) {
        float4 t = {0.f, 0.f, 0.f, 0.f};
        #pragma unroll
        for (int j = 0; j < 8; ++j) {
            float4 v = *(const float4*)&xr_s[j][tid * 4];
            t.x += v.x; t.y += v.y; t.z += v.z; t.w += v.w;
        }
        atomicAdd(&emp[k * DD + tid * 4 + 0], t.x);
        atomicAdd(&emp[k * DD + tid * 4 + 1], t.y);
        atomicAdd(&emp[k * DD + tid * 4 + 2], t.z);
        atomicAdd(&emp[k * DD + tid * 4 + 3], t.w);
    }
}

// ---------------------------------------------------------------------------
// K4: grid = KK x 8 slabs (2048 elems). Items split across the 4 waves
// (depth/4); within an item the wave streams the slab as 8 contiguous 1KB
// coalesced float4 transactions with 8 independent acc chains (MLP).
// Cross-wave combine in LDS, then centered covariance + scalar accumulate.
// (R5's item-major 64KB-strided gather was 58us @ 98GB/s — latency/L2-set
// pathology. This layout reads the same bytes at streaming BW.)
// ---------------------------------------------------------------------------
__global__ __launch_bounds__(256) void k_redfinal(
    const float* __restrict__ part, const float* __restrict__ emp,
    const float* __restrict__ cw, const float* __restrict__ centers,
    const int* __restrict__ ist, const int* __restrict__ ien,
    float* __restrict__ outscalars)
{
    const int k = blockIdx.x >> 3;
    const int p = blockIdx.x & 7;
    const int i0 = ist[k], i1 = ien[k];
    const int tid = threadIdx.x;
    const int w = tid >> 6, lane = tid & 63;
    const float wgt = cw[k];
    const float inv = 1.0f / (wgt + 1e-7f);

    __shared__ float mu_s[DD], emp_s[DD];
    __shared__ float red[4][RSLAB];      // 32 KB

    if (tid < DD) {
        float e = emp[k * DD + tid];
        emp_s[tid] = e;
        mu_s[tid] = e * inv;
    }

    float4 acc[8];
    #pragma unroll
    for (int c = 0; c < 8; ++c) acc[c] = make_float4(0.f, 0.f, 0.f, 0.f);

    const int base = p * RSLAB;
    for (int it = i0 + w; it < i1; it += 4) {
        const float* pb = part + (size_t)it * (DD * DD) + base;
        #pragma unroll
        for (int c = 0; c < 8; ++c) {
            float4 v = *(const float4*)&pb[c * 256 + lane * 4];
            acc[c].x += v.x; acc[c].y += v.y; acc[c].z += v.z; acc[c].w += v.w;
        }
    }
    #pragma unroll
    for (int c = 0; c < 8; ++c)
        *(float4*)&red[w][c * 256 + lane * 4] = acc[c];
    __syncthreads();

    float ds = 0.f, os = 0.f, mm = 0.f;
    #pragma unroll
    for (int jj = 0; jj < 8; ++jj) {
        int el = tid * 8 + jj;
        float sx = red[0][el] + red[1][el] + red[2][el] + red[3][el];
        int gel = base + el;
        int d = gel >> 7, e = gel & 127;
        float ctv = sx - mu_s[d] * emp_s[e] - emp_s[d] * mu_s[e]
                  + wgt * mu_s[d] * mu_s[e];
        float v = ctv * inv;
        if (d == e) { float t = v - 1.f; ds += t * t; }
        else        { os += v * v; }
    }
    if (p == 0 && tid < DD) {
        float t = mu_s[tid] - centers[k * DD + tid];
        mm = t * t;
    }

    #pragma unroll
    for (int off = 32; off > 0; off >>= 1) {
        ds += __shfl_down(ds, off);
        os += __shfl_down(os, off);
        mm += __shfl_down(mm, off);
    }
    __shared__ float rds[4], ros[4], rmm[4];
    if (lane == 0) { rds[w] = ds; ros[w] = os; rmm[w] = mm; }
    __syncthreads();
    if (tid == 0) {
        float DS = rds[0] + rds[1] + rds[2] + rds[3];
        float OS = ros[0] + ros[1] + ros[2] + ros[3];
        float MM = rmm[0] + rmm[1] + rmm[2] + rmm[3];
        const float bd = (float)BB * (float)DD;
        atomicAdd(&outscalars[0], wgt * MM / bd);
        atomicAdd(&outscalars[1], wgt * DS / bd + wgt * OS / (bd * (float)(DD - 1)));
    }
}

// ---------------------------------------------------------------------------
extern "C" void kernel_launch(void* const* d_in, const int* in_sizes, int n_in,
                              void* d_out, int out_size, void* d_ws, size_t ws_size,
                              hipStream_t stream) {
    const float* x = (const float*)d_in[0];
    const float* centers = (const float*)d_in[1];
    float* out = (float*)d_out;
    float* outscalars = out + (size_t)BB * KK;

    char* ws = (char*)d_ws;
    size_t off = 0;
    float* part    = (float*)(ws + off); off += (size_t)MAXITEMS * DD * DD * 4; // 16 MB
    float* emp     = (float*)(ws + off); off += KK * DD * 4;                    // 32 KB
    int*   sorted  = (int*)  (ws + off); off += BB * 4;
    int*   assign  = (int*)  (ws + off); off += BB * 4;
    int4*  items   = (int4*) (ws + off); off += MAXITEMS * 16;
    float* cw      = (float*)(ws + off); off += 256;
    int*   itemcnt = (int*)  (ws + off); off += 256;
    int*   ist     = (int*)  (ws + off); off += 256;
    int*   ien     = (int*)  (ws + off); off += 256;

    k_rows    <<<256, 256,  0, stream>>>(x, centers, out, assign, outscalars, emp);
    k_sort    <<<1,   1024, 0, stream>>>(assign, sorted, cw, items, itemcnt, ist, ien);
    k_seg     <<<MAXITEMS, 256, 0, stream>>>(x, sorted, items, itemcnt, part, emp);
    k_redfinal<<<KK * 8, 256, 0, stream>>>(part, emp, cw, centers, ist, ien,
                                           outscalars);
}